// Round 13
// baseline (218.916 us; speedup 1.0000x reference)
//
#include <hip/hip_runtime.h>

typedef unsigned short u16;
typedef __attribute__((ext_vector_type(4))) float f32x4;
typedef __attribute__((ext_vector_type(16))) float f32x16;
typedef __attribute__((ext_vector_type(8))) __bf16 bf16x8;
typedef __attribute__((ext_vector_type(8))) unsigned short u16x8;
typedef __attribute__((ext_vector_type(2))) unsigned u32x2;

#define L2E 1.44269504088896340736f

#if __has_builtin(__builtin_amdgcn_exp2f)
#define EXP2(x) __builtin_amdgcn_exp2f(x)
#else
#define EXP2(x) exp2f(x)
#endif

__device__ __forceinline__ u16 f2bf(float f) {
  unsigned u = __float_as_uint(f);
  u += 0x7fffu + ((u >> 16) & 1u);
  return (u16)(u >> 16);
}

__device__ __forceinline__ unsigned pk2(float a, float b) {
  __bf16 x = (__bf16)a, y = (__bf16)b;
  unsigned short ux = __builtin_bit_cast(unsigned short, x);
  unsigned short uy = __builtin_bit_cast(unsigned short, y);
  return (unsigned)ux | ((unsigned)uy << 16);
}

__device__ __forceinline__ bf16x8 as_bf(uint4 v) { return __builtin_bit_cast(bf16x8, v); }

__device__ __forceinline__ u32x2 plswap(unsigned a, unsigned b) {
#if __has_builtin(__builtin_amdgcn_permlane32_swap)
  auto t = __builtin_amdgcn_permlane32_swap(a, b, false, false);
  return __builtin_bit_cast(u32x2, t);
#else
  unsigned pa = (unsigned)__shfl_xor((int)a, 32, 64);
  unsigned pb = (unsigned)__shfl_xor((int)b, 32, 64);
  const bool hi = (threadIdx.x & 32) != 0;
  u32x2 r;
  r.x = hi ? pb : a;
  r.y = hi ? b : pa;
  return r;
#endif
}

__device__ __forceinline__ void gl2lds16(const void* g, void* l) {
  __builtin_amdgcn_global_load_lds((const __attribute__((address_space(1))) void*)g,
                                   (__attribute__((address_space(3))) void*)l, 16, 0, 0);
}

// ---------------- prep: cvt_hs (blocks 0..6143) + cvt_w (blocks 6144..8447) ----------------
__global__ void prep(const float* __restrict__ hs, const float* __restrict__ Wq,
                     const float* __restrict__ Wk, const float* __restrict__ Wv,
                     const float* __restrict__ Wo, u16* __restrict__ hsb,
                     u16* __restrict__ wt, u16* __restrict__ wot) {
  const int blk = blockIdx.x;
  const int tid = threadIdx.x;
  if (blk < 6144) {
    const int i = blk * 256 + tid;
    float4 v = ((const float4*)hs)[i];
    ushort4 o;
    o.x = f2bf(v.x); o.y = f2bf(v.y); o.z = f2bf(v.z); o.w = f2bf(v.w);
    ((ushort4*)hsb)[i] = o;
    return;
  }
  __shared__ float ts[32][33];
  const int idx = blk - 6144;
  const int w = idx / 576;
  const int rem = idx % 576;
  const int n0 = (rem % 24) * 32, k0 = (rem / 24) * 32;
  const float* src = (w == 0) ? Wq : (w == 1) ? Wk : (w == 2) ? Wv : Wo;
  u16* dst = (w < 3) ? (wt + (size_t)w * 768 * 768) : wot;
  const float scale = (w == 0) ? 0.125f * L2E : 1.0f;
  const int tx = tid & 31, ty = tid >> 5;
#pragma unroll
  for (int j = 0; j < 4; ++j)
    ts[ty + 8 * j][tx] = src[(size_t)(k0 + ty + 8 * j) * 768 + n0 + tx];
  __syncthreads();
#pragma unroll
  for (int j = 0; j < 4; ++j)
    dst[(size_t)(n0 + ty + 8 * j) * 768 + k0 + tx] = f2bf(ts[tx][ty + 8 * j] * scale);
}

// ---------------- GEMM v6: 256x256 8-phase (T3+T4), 512 threads, 128KB dynamic LDS ----------
// 8 waves (2M x 4N), per-wave 128x64 out. BK=64; 2 K-tiles per iteration; per K-tile 4
// quadrant-phases {ds_read frags | 2 stage issues -> barrier -> 16 MFMA -> barrier}.
// Tile t+1 staged into the idle buffer while the other computes; ONE vmcnt(0) per
// 4-phase group (before its final barrier). LDS rows 128B, slot-XOR (row&7) swizzle via
// pre-swizzled global source (measured 0 bank conflicts with this family, R10).
template <int MODE>
__global__ void __launch_bounds__(512, 2)
gemm256(const u16* __restrict__ A, const u16* __restrict__ Bt,
        const float* __restrict__ b0, const float* __restrict__ b1,
        const float* __restrict__ b2, void* __restrict__ Cout,
        int M, int N, int K, int nbx) {
  extern __shared__ u16 lds[];  // [2][A:16384 | B:16384] u16 = 128 KB
  const int tid = threadIdx.x;  // 0..511
  const int lane = tid & 63, wid = tid >> 6;
  const int wm = wid >> 2, wn = wid & 3;
  const int l15 = lane & 15, lg = lane >> 4;
  const int r7 = l15 & 7;

  const int nwg = gridDim.x;
  const int cpx = nwg >> 3;  // nwg % 8 == 0
  const int p = blockIdx.x;
  const int wg = (p & 7) * cpx + (p >> 3);
  const int mblk = (wg / nbx) * 256, nblk = (wg % nbx) * 256;

  f32x4 acc[8][4] = {};

  // staging: thread t covers row j*64 + (t>>3), physical 16B-slot t&7,
  // global slot pre-swizzled so phys slot s holds global slot s ^ (row&7)
  const int srow = tid >> 3;                 // 0..63
  const int sx = (tid & 7) ^ (srow & 7);
  const u16* Ag = A + (size_t)(mblk + srow) * K + 8 * sx;
  const u16* Bg = Bt + (size_t)(nblk + srow) * K + 8 * sx;

#define STA(ob, skt, j) \
  gl2lds16(Ag + (size_t)(j) * 64 * K + (size_t)(skt) * 64, lds + (ob) * 32768 + (j) * 4096 + tid * 8)
#define STB(ob, skt, j) \
  gl2lds16(Bg + (size_t)(j) * 64 * K + (size_t)(skt) * 64, lds + (ob) * 32768 + 16384 + (j) * 4096 + tid * 8)

  // frag-read bases (u16 idx): A row = wm*128 + mh*64 + 16m + l15; slot (4kk+lg)^r7
  const int sl0 = 8 * (lg ^ r7);
  const int sl1 = 8 * ((4 + lg) ^ r7);
  const int arb = (wm * 128 + l15) * 64;
  const int brb = (wn * 64 + l15) * 64;

#define GROUP(bb, dost, skt)                                                                 \
  {                                                                                          \
    bf16x8 af[4][2], bfr[2][2];                                                              \
    _Pragma("unroll") for (int ph = 0; ph < 4; ++ph) {                                       \
      const int mh = ph >> 1, nh = ph & 1;                                                   \
      if (nh == 0) {                                                                         \
        _Pragma("unroll") for (int m = 0; m < 4; ++m) {                                      \
          af[m][0] = as_bf(*(const uint4*)&lds[(bb) * 32768 + arb + mh * 4096 + m * 1024 + sl0]); \
          af[m][1] = as_bf(*(const uint4*)&lds[(bb) * 32768 + arb + mh * 4096 + m * 1024 + sl1]); \
        }                                                                                    \
      }                                                                                      \
      _Pragma("unroll") for (int n = 0; n < 2; ++n) {                                        \
        bfr[n][0] = as_bf(*(const uint4*)&lds[(bb) * 32768 + 16384 + brb + nh * 2048 + n * 1024 + sl0]); \
        bfr[n][1] = as_bf(*(const uint4*)&lds[(bb) * 32768 + 16384 + brb + nh * 2048 + n * 1024 + sl1]); \
      }                                                                                      \
      if (dost) {                                                                            \
        if (ph == 0) { STA(bb ^ 1, skt, 0); STA(bb ^ 1, skt, 1); }                           \
        if (ph == 1) { STA(bb ^ 1, skt, 2); STA(bb ^ 1, skt, 3); }                           \
        if (ph == 2) { STB(bb ^ 1, skt, 0); STB(bb ^ 1, skt, 1); }                           \
        if (ph == 3) { STB(bb ^ 1, skt, 2); STB(bb ^ 1, skt, 3); }                           \
      }                                                                                      \
      __builtin_amdgcn_s_barrier();                                                          \
      __builtin_amdgcn_s_setprio(1);                                                         \
      _Pragma("unroll") for (int m = 0; m < 4; ++m)                                          \
        _Pragma("unroll") for (int n = 0; n < 2; ++n) {                                      \
          acc[mh * 4 + m][nh * 2 + n] = __builtin_amdgcn_mfma_f32_16x16x32_bf16(             \
              af[m][0], bfr[n][0], acc[mh * 4 + m][nh * 2 + n], 0, 0, 0);                    \
          acc[mh * 4 + m][nh * 2 + n] = __builtin_amdgcn_mfma_f32_16x16x32_bf16(             \
              af[m][1], bfr[n][1], acc[mh * 4 + m][nh * 2 + n], 0, 0, 0);                    \
        }                                                                                    \
      __builtin_amdgcn_s_setprio(0);                                                         \
      if (ph == 3) asm volatile("s_waitcnt vmcnt(0)" ::: "memory");                          \
      __builtin_amdgcn_s_barrier();                                                          \
    }                                                                                        \
    __builtin_amdgcn_sched_barrier(0);                                                       \
  }

  // prologue: stage tile 0 -> buf0, drain, barrier
#pragma unroll
  for (int j = 0; j < 4; ++j) { STA(0, 0, j); STB(0, 0, j); }
  asm volatile("s_waitcnt vmcnt(0)" ::: "memory");
  __builtin_amdgcn_s_barrier();
  __builtin_amdgcn_sched_barrier(0);

  const int nt = K >> 6;  // 12 for K=768 (even)
#pragma unroll 1
  for (int it = 0; it < (nt >> 1); ++it) {
    GROUP(0, true, 2 * it + 1);                       // compute T(2it) from buf0, stage T(2it+1)->buf1
    const bool more = (2 * it + 2) < nt;
    GROUP(1, more, 2 * it + 2);                       // compute T(2it+1) from buf1, stage T(2it+2)->buf0
  }
#undef GROUP
#undef STA
#undef STB

#pragma unroll
  for (int ni = 0; ni < 4; ++ni) {
    const int col = nblk + wn * 64 + 16 * ni + l15;
    float bias;
    if (MODE == 0) {
      if (col < 768) bias = b0[col] * (0.125f * L2E);
      else if (col < 1536) bias = b1[col - 768];
      else bias = b2[col - 1536];
    } else {
      bias = b0[col];
    }
#pragma unroll
    for (int mi = 0; mi < 8; ++mi) {
#pragma unroll
      for (int r = 0; r < 4; ++r) {
        const int row = mblk + wm * 128 + 16 * mi + 4 * lg + r;
        const float v = acc[mi][ni][r] + bias;
        if (MODE == 0)
          ((u16*)Cout)[(size_t)row * N + col] = f2bf(v);
        else
          ((float*)Cout)[(size_t)row * N + col] = v;
      }
    }
  }
}

// ---------------- V transpose: vt[b][h][hd][s] = qkv[b][s][1536 + h*64 + hd] ----------------
__global__ void tr_v(const u16* __restrict__ qkv, u16* __restrict__ vt) {
  __shared__ u16 t[64][72];
  const int tid = threadIdx.x;
  const int st = blockIdx.x, h = blockIdx.y, b = blockIdx.z;
  const u16* vsrc = qkv + (size_t)b * 2048 * 2304 + 1536 + h * 64;
  const int s0 = st * 64;
#pragma unroll
  for (int i = 0; i < 2; ++i) {
    const int seg = tid + 256 * i;
    const int row = seg >> 3, slot = seg & 7;
    *(uint4*)&t[row][slot * 8] = *(const uint4*)(vsrc + (size_t)(s0 + row) * 2304 + slot * 8);
  }
  __syncthreads();
  u16* dst = vt + (size_t)(b * 12 + h) * 64 * 2048;
#pragma unroll
  for (int i = 0; i < 2; ++i) {
    const int seg = tid + 256 * i;
    const int hd = seg >> 3, j0 = (seg & 7) * 8;
    u16x8 o;
#pragma unroll
    for (int j = 0; j < 8; ++j) o[j] = t[j0 + j][hd];
    *(u16x8*)(dst + (size_t)hd * 2048 + s0 + j0) = o;
  }
}

// ---------------- flash attention v6 (R11): static-max softmax, p = 2^s ----------------
__global__ void __launch_bounds__(256, 3)
attn_fwd(const u16* __restrict__ qkv, const u16* __restrict__ vt, u16* __restrict__ ctx) {
  __shared__ u16 Ks[2][64 * 64];
  __shared__ u16 Vs[2][64 * 64];

  const int tid = threadIdx.x;
  const int lane = tid & 63, wid = tid >> 6;
  const int l31 = lane & 31, H = lane >> 5;
  const int r7 = l31 & 7;

  const int p = blockIdx.x;
  const int l = 96 * (p & 7) + (p >> 3);
  const int qb = l & 15;
  const int hb = l >> 4;
  const int h = hb % 12;
  const int b = hb / 12;

  const u16* qbase = qkv + (size_t)b * 2048 * 2304 + h * 64;
  const u16* kbase = qbase + 768;
  const u16* vbase = vt + (size_t)(b * 12 + h) * 64 * 2048;

  const int srow = tid >> 3;
  const int sx = (tid & 7) ^ (srow & 7);
  const int dseg = (tid & ~63) * 8;

  const u16* kp0 = kbase + (size_t)srow * 2304 + 8 * sx;
  const u16* kp1 = kbase + (size_t)(srow + 32) * 2304 + 8 * sx;
  const u16* vp0 = vbase + (size_t)srow * 2048 + 8 * sx;
  const u16* vp1 = vbase + (size_t)(srow + 32) * 2048 + 8 * sx;

  unsigned koff[2][4];
#pragma unroll
  for (int t32 = 0; t32 < 2; ++t32)
#pragma unroll
    for (int ks = 0; ks < 4; ++ks)
      koff[t32][ks] = (32 * t32 + l31) * 64 + 8 * ((2 * ks + H) ^ r7);

  const int q0 = qb * 128 + wid * 32;
  bf16x8 qf[4];
#pragma unroll
  for (int ks = 0; ks < 4; ++ks)
    qf[ks] = as_bf(*(const uint4*)(qbase + (size_t)(q0 + l31) * 2304 + 16 * ks + 8 * H));

  float lsum = 0.f;
  f32x16 o[2] = {};

#define STAGE(buf)                              \
  {                                             \
    gl2lds16(kp0, &Ks[buf][dseg]);              \
    gl2lds16(kp1, &Ks[buf][dseg + 2048]);       \
    gl2lds16(vp0, &Vs[buf][dseg]);              \
    gl2lds16(vp1, &Vs[buf][dseg + 2048]);       \
    kp0 += 64 * 2304; kp1 += 64 * 2304;         \
    vp0 += 64; vp1 += 64;                       \
  }

#define PHASE(CUR)                                                                        \
  {                                                                                       \
    f32x16 st[2] = {};                                                                    \
    __builtin_amdgcn_s_setprio(1);                                                        \
    _Pragma("unroll") for (int k32 = 0; k32 < 2; ++k32)                                   \
        _Pragma("unroll") for (int ks = 0; ks < 4; ++ks) {                                \
      bf16x8 kf = as_bf(*(const uint4*)&Ks[CUR][koff[k32][ks]]);                          \
      st[k32] = __builtin_amdgcn_mfma_f32_32x32x16_bf16(kf, qf[ks], st[k32], 0, 0, 0);    \
    }                                                                                     \
    __builtin_amdgcn_s_setprio(0);                                                        \
    float s0 = 0.f, s1 = 0.f, s2 = 0.f, s3 = 0.f;                                         \
    _Pragma("unroll") for (int k32 = 0; k32 < 2; ++k32)                                   \
        _Pragma("unroll") for (int r = 0; r < 16; r += 4) {                               \
      float e0 = EXP2(st[k32][r + 0]);                                                    \
      float e1 = EXP2(st[k32][r + 1]);                                                    \
      float e2 = EXP2(st[k32][r + 2]);                                                    \
      float e3 = EXP2(st[k32][r + 3]);                                                    \
      st[k32][r + 0] = e0; st[k32][r + 1] = e1;                                           \
      st[k32][r + 2] = e2; st[k32][r + 3] = e3;                                           \
      s0 += e0; s1 += e1; s2 += e2; s3 += e3;                                             \
    }                                                                                     \
    lsum += (s0 + s1) + (s2 + s3);                                                        \
    bf16x8 pf[4];                                                                         \
    _Pragma("unroll") for (int ks = 0; ks < 4; ++ks) {                                    \
      const int k32 = ks >> 1, rb = 8 * (ks & 1);                                         \
      unsigned a0 = pk2(st[k32][rb + 0], st[k32][rb + 1]);                                \
      unsigned a1 = pk2(st[k32][rb + 2], st[k32][rb + 3]);                                \
      unsigned a2 = pk2(st[k32][rb + 4], st[k32][rb + 5]);                                \
      unsigned a3 = pk2(st[k32][rb + 6], st[k32][rb + 7]);                                \
      u32x2 s02 = plswap(a0, a2);                                                         \
      u32x2 s13 = plswap(a1, a3);                                                         \
      uint4 w;                                                                            \
      w.x = s02.x; w.y = s13.x; w.z = s02.y; w.w = s13.y;                                 \
      pf[ks] = as_bf(w);                                                                  \
    }                                                                                     \
    __builtin_amdgcn_s_setprio(1);                                                        \
    _Pragma("unroll") for (int d32 = 0; d32 < 2; ++d32)                                   \
        _Pragma("unroll") for (int ks = 0; ks < 4; ++ks) {                                \
      bf16x8 vf = as_bf(*(const uint4*)&Vs[CUR][koff[d32][ks]]);                          \
      o[d32] = __builtin_amdgcn_mfma_f32_32x32x16_bf16(vf, pf[ks], o[d32], 0, 0, 0);      \
    }                                                                                     \
    __builtin_amdgcn_s_setprio(0);                                                        \
    __syncthreads();                                                                      \
  }

  STAGE(0);
  __syncthreads();

#pragma unroll 1
  for (int cc = 0; cc < 16; ++cc) {
    const int c2 = 2 * cc;
    STAGE(1);
    PHASE(0);
    if (c2 + 2 < 32) STAGE(0);
    PHASE(1);
  }
#undef PHASE
#undef STAGE

  const float ls = lsum + __shfl_xor(lsum, 32, 64);
  const float inv = 1.0f / ls;
  const size_t rowoff = ((size_t)b * 2048 + q0 + l31) * 768 + h * 64;
#pragma unroll
  for (int d32 = 0; d32 < 2; ++d32)
#pragma unroll
    for (int g = 0; g < 4; ++g) {
      uint2 w;
      w.x = pk2(o[d32][4 * g + 0] * inv, o[d32][4 * g + 1] * inv);
      w.y = pk2(o[d32][4 * g + 2] * inv, o[d32][4 * g + 3] * inv);
      *(uint2*)&ctx[rowoff + 32 * d32 + 8 * g + 4 * H] = w;
    }
}

// ---------------- launch ----------------
extern "C" void kernel_launch(void* const* d_in, const int* in_sizes, int n_in,
                              void* d_out, int out_size, void* d_ws, size_t ws_size,
                              hipStream_t stream) {
  const float* hs = (const float*)d_in[0];
  const float* Wq = (const float*)d_in[1];
  const float* bq = (const float*)d_in[2];
  const float* Wk = (const float*)d_in[3];
  const float* bk = (const float*)d_in[4];
  const float* Wv = (const float*)d_in[5];
  const float* bv = (const float*)d_in[6];
  const float* Wo = (const float*)d_in[7];
  const float* bo = (const float*)d_in[8];

  char* ws = (char*)d_ws;
  u16* hsb = (u16*)ws;                       // 8192*768 bf16
  u16* wt  = (u16*)(ws + 12582912);          // 2304*768 bf16
  u16* wot = (u16*)(ws + 16121856);          // 768*768 bf16
  u16* qkv = (u16*)(ws + 17301504);          // 8192*2304 bf16
  u16* vt  = (u16*)(ws + 55050240);          // 48*64*2048 bf16
  u16* ctx = (u16*)(ws + 67633152);          // 8192*768 bf16

  prep<<<dim3(8448), dim3(256), 0, stream>>>(hs, Wq, Wk, Wv, Wo, hsb, wt, wot);
  gemm256<0><<<dim3(288), dim3(512), 131072, stream>>>(hsb, wt, bq, bk, bv, (void*)qkv,
                                                       8192, 2304, 768, 9);
  tr_v<<<dim3(32, 12, 4), dim3(256), 0, stream>>>(qkv, vt);
  attn_fwd<<<dim3(768), dim3(256), 0, stream>>>(qkv, vt, ctx);
  gemm256<1><<<dim3(96), dim3(512), 131072, stream>>>(ctx, wot, bo, bo, bo, d_out,
                                                      8192, 768, 768, 3);
}

// Round 14
// 179.653 us; speedup vs baseline: 1.2186x; 1.2186x over previous
//
#include <hip/hip_runtime.h>

typedef unsigned short u16;
typedef __attribute__((ext_vector_type(4))) float f32x4;
typedef __attribute__((ext_vector_type(16))) float f32x16;
typedef __attribute__((ext_vector_type(8))) __bf16 bf16x8;
typedef __attribute__((ext_vector_type(8))) unsigned short u16x8;
typedef __attribute__((ext_vector_type(2))) unsigned u32x2;

#define L2E 1.44269504088896340736f

#if __has_builtin(__builtin_amdgcn_exp2f)
#define EXP2(x) __builtin_amdgcn_exp2f(x)
#else
#define EXP2(x) exp2f(x)
#endif

__device__ __forceinline__ u16 f2bf(float f) {
  unsigned u = __float_as_uint(f);
  u += 0x7fffu + ((u >> 16) & 1u);
  return (u16)(u >> 16);
}

__device__ __forceinline__ unsigned pk2(float a, float b) {
  __bf16 x = (__bf16)a, y = (__bf16)b;
  unsigned short ux = __builtin_bit_cast(unsigned short, x);
  unsigned short uy = __builtin_bit_cast(unsigned short, y);
  return (unsigned)ux | ((unsigned)uy << 16);
}

__device__ __forceinline__ bf16x8 as_bf(uint4 v) { return __builtin_bit_cast(bf16x8, v); }

__device__ __forceinline__ u32x2 plswap(unsigned a, unsigned b) {
#if __has_builtin(__builtin_amdgcn_permlane32_swap)
  auto t = __builtin_amdgcn_permlane32_swap(a, b, false, false);
  return __builtin_bit_cast(u32x2, t);
#else
  unsigned pa = (unsigned)__shfl_xor((int)a, 32, 64);
  unsigned pb = (unsigned)__shfl_xor((int)b, 32, 64);
  const bool hi = (threadIdx.x & 32) != 0;
  u32x2 r;
  r.x = hi ? pb : a;
  r.y = hi ? b : pa;
  return r;
#endif
}

__device__ __forceinline__ void gl2lds16(const void* g, void* l) {
  __builtin_amdgcn_global_load_lds((const __attribute__((address_space(1))) void*)g,
                                   (__attribute__((address_space(3))) void*)l, 16, 0, 0);
}

// ---------------- prep: cvt_hs (blocks 0..6143) + cvt_w (blocks 6144..8447) ----------------
__global__ void prep(const float* __restrict__ hs, const float* __restrict__ Wq,
                     const float* __restrict__ Wk, const float* __restrict__ Wv,
                     const float* __restrict__ Wo, u16* __restrict__ hsb,
                     u16* __restrict__ wt, u16* __restrict__ wot) {
  const int blk = blockIdx.x;
  const int tid = threadIdx.x;
  if (blk < 6144) {
    const int i = blk * 256 + tid;
    float4 v = ((const float4*)hs)[i];
    ushort4 o;
    o.x = f2bf(v.x); o.y = f2bf(v.y); o.z = f2bf(v.z); o.w = f2bf(v.w);
    ((ushort4*)hsb)[i] = o;
    return;
  }
  __shared__ float ts[32][33];
  const int idx = blk - 6144;
  const int w = idx / 576;
  const int rem = idx % 576;
  const int n0 = (rem % 24) * 32, k0 = (rem / 24) * 32;
  const float* src = (w == 0) ? Wq : (w == 1) ? Wk : (w == 2) ? Wv : Wo;
  u16* dst = (w < 3) ? (wt + (size_t)w * 768 * 768) : wot;
  const float scale = (w == 0) ? 0.125f * L2E : 1.0f;
  const int tx = tid & 31, ty = tid >> 5;
#pragma unroll
  for (int j = 0; j < 4; ++j)
    ts[ty + 8 * j][tx] = src[(size_t)(k0 + ty + 8 * j) * 768 + n0 + tx];
  __syncthreads();
#pragma unroll
  for (int j = 0; j < 4; ++j)
    dst[(size_t)(n0 + ty + 8 * j) * 768 + k0 + tx] = f2bf(ts[tx][ty + 8 * j] * scale);
}

// ---------------- GEMM v7: 256x256 8-phase with GENUINELY counted vmcnt ----------------
// 8 waves (2M x 4N), per-wave 128x64 out, BK=64, 128KB LDS (2 buf).
// Stage order per group (tile T+1): ph0:B0,B1  ph1:B2,B3  ph2:A0,A2  ph3:A1,A3.
// Every phase reads ALL B chunks; A-half mh=0 chunks {0,2}, mh=1 chunks {1,3}.
// FIFO waits: vmcnt(2) @ph3-end (all B + A0,A2 of T+1 landed; A1,A3 in flight),
// vmcnt(4) @ph1-end (retire previous tile's A1,A3 before ph2 reads them).
// Never drains to 0 in steady state. Last group (no staging) downgrades to vmcnt(0).
template <int MODE>
__global__ void __launch_bounds__(512, 2)
gemm256(const u16* __restrict__ A, const u16* __restrict__ Bt,
        const float* __restrict__ b0, const float* __restrict__ b1,
        const float* __restrict__ b2, void* __restrict__ Cout,
        int M, int N, int K, int nbx) {
  extern __shared__ u16 lds[];  // [2][A:16384 | B:16384] u16 = 128 KB
  const int tid = threadIdx.x;  // 0..511
  const int lane = tid & 63, wid = tid >> 6;
  const int wm = wid >> 2, wn = wid & 3;
  const int l15 = lane & 15, lg = lane >> 4;
  const int r7 = l15 & 7;

  const int nwg = gridDim.x;
  const int cpx = nwg >> 3;  // nwg % 8 == 0
  const int p = blockIdx.x;
  const int wg = (p & 7) * cpx + (p >> 3);
  const int mblk = (wg / nbx) * 256, nblk = (wg % nbx) * 256;

  f32x4 acc[8][4] = {};

  // staging: chunk = 64 rows; thread covers row tid>>3, phys slot tid&7,
  // global slot pre-swizzled (^ row&7) so frag reads are conflict-free
  const int srow = tid >> 3;
  const int sx = (tid & 7) ^ (srow & 7);
  const u16* Ag = A + (size_t)(mblk + srow) * K + 8 * sx;
  const u16* Bg = Bt + (size_t)(nblk + srow) * K + 8 * sx;

#define STA(ob, skt, j) \
  gl2lds16(Ag + (size_t)(j) * 64 * K + (size_t)(skt) * 64, lds + (ob) * 32768 + (j) * 4096 + tid * 8)
#define STB(ob, skt, j) \
  gl2lds16(Bg + (size_t)(j) * 64 * K + (size_t)(skt) * 64, lds + (ob) * 32768 + 16384 + (j) * 4096 + tid * 8)

  const int sl0 = 8 * (lg ^ r7);
  const int sl1 = 8 * ((4 + lg) ^ r7);
  const int arb = (wm * 128 + l15) * 64;
  const int brb = (wn * 64 + l15) * 64;

  // one phase: frag ds_reads | stage 2 chunks | barrier | 16 MFMA | [wait] | barrier
#define GROUP(bb, dost, skt)                                                                 \
  {                                                                                          \
    bf16x8 af[4][2], bfr[2][2];                                                              \
    _Pragma("unroll") for (int ph = 0; ph < 4; ++ph) {                                       \
      const int mh = ph >> 1, nh = ph & 1;                                                   \
      if (nh == 0) {                                                                         \
        _Pragma("unroll") for (int m = 0; m < 4; ++m) {                                      \
          af[m][0] = as_bf(*(const uint4*)&lds[(bb) * 32768 + arb + mh * 4096 + m * 1024 + sl0]); \
          af[m][1] = as_bf(*(const uint4*)&lds[(bb) * 32768 + arb + mh * 4096 + m * 1024 + sl1]); \
        }                                                                                    \
      }                                                                                      \
      _Pragma("unroll") for (int n = 0; n < 2; ++n) {                                        \
        bfr[n][0] = as_bf(*(const uint4*)&lds[(bb) * 32768 + 16384 + brb + nh * 2048 + n * 1024 + sl0]); \
        bfr[n][1] = as_bf(*(const uint4*)&lds[(bb) * 32768 + 16384 + brb + nh * 2048 + n * 1024 + sl1]); \
      }                                                                                      \
      if (dost) {                                                                            \
        if (ph == 0) { STB(bb ^ 1, skt, 0); STB(bb ^ 1, skt, 1); }                           \
        if (ph == 1) { STB(bb ^ 1, skt, 2); STB(bb ^ 1, skt, 3); }                           \
        if (ph == 2) { STA(bb ^ 1, skt, 0); STA(bb ^ 1, skt, 2); }                           \
        if (ph == 3) { STA(bb ^ 1, skt, 1); STA(bb ^ 1, skt, 3); }                           \
      }                                                                                      \
      __builtin_amdgcn_s_barrier();                                                          \
      __builtin_amdgcn_s_setprio(1);                                                         \
      _Pragma("unroll") for (int m = 0; m < 4; ++m)                                          \
        _Pragma("unroll") for (int n = 0; n < 2; ++n) {                                      \
          acc[mh * 4 + m][nh * 2 + n] = __builtin_amdgcn_mfma_f32_16x16x32_bf16(             \
              af[m][0], bfr[n][0], acc[mh * 4 + m][nh * 2 + n], 0, 0, 0);                    \
          acc[mh * 4 + m][nh * 2 + n] = __builtin_amdgcn_mfma_f32_16x16x32_bf16(             \
              af[m][1], bfr[n][1], acc[mh * 4 + m][nh * 2 + n], 0, 0, 0);                    \
        }                                                                                    \
      __builtin_amdgcn_s_setprio(0);                                                         \
      if (ph == 1) {                                                                         \
        if (dost) asm volatile("s_waitcnt vmcnt(4)" ::: "memory");                           \
        else      asm volatile("s_waitcnt vmcnt(0)" ::: "memory");                           \
      }                                                                                      \
      if (ph == 3) {                                                                         \
        if (dost) asm volatile("s_waitcnt vmcnt(2)" ::: "memory");                           \
        else      asm volatile("s_waitcnt vmcnt(0)" ::: "memory");                           \
      }                                                                                      \
      __builtin_amdgcn_s_barrier();                                                          \
    }                                                                                        \
    __builtin_amdgcn_sched_barrier(0);                                                       \
  }

  // prologue: stage tile 0 -> buf0, drain, barrier
#pragma unroll
  for (int j = 0; j < 4; ++j) { STB(0, 0, j); }
#pragma unroll
  for (int j = 0; j < 4; ++j) { STA(0, 0, j); }
  asm volatile("s_waitcnt vmcnt(0)" ::: "memory");
  __builtin_amdgcn_s_barrier();
  __builtin_amdgcn_sched_barrier(0);

  const int nt = K >> 6;  // 12 for K=768 (even)
#pragma unroll 1
  for (int it = 0; it < (nt >> 1); ++it) {
    GROUP(0, true, 2 * it + 1);
    const bool more = (2 * it + 2) < nt;
    GROUP(1, more, 2 * it + 2);
  }
#undef GROUP
#undef STA
#undef STB

#pragma unroll
  for (int ni = 0; ni < 4; ++ni) {
    const int col = nblk + wn * 64 + 16 * ni + l15;
    float bias;
    if (MODE == 0) {
      if (col < 768) bias = b0[col] * (0.125f * L2E);
      else if (col < 1536) bias = b1[col - 768];
      else bias = b2[col - 1536];
    } else {
      bias = b0[col];
    }
#pragma unroll
    for (int mi = 0; mi < 8; ++mi) {
#pragma unroll
      for (int r = 0; r < 4; ++r) {
        const int row = mblk + wm * 128 + 16 * mi + 4 * lg + r;
        const float v = acc[mi][ni][r] + bias;
        if (MODE == 0)
          ((u16*)Cout)[(size_t)row * N + col] = f2bf(v);
        else
          ((float*)Cout)[(size_t)row * N + col] = v;
      }
    }
  }
}

// ---------------- GEMM 128x128 triple-buffered (R11, proven) for the O-projection ------------
template <int MODE>
__global__ void gemm_bt(const u16* __restrict__ A, const u16* __restrict__ Bt,
                        const float* __restrict__ b0, const float* __restrict__ b1,
                        const float* __restrict__ b2, void* __restrict__ Cout,
                        int M, int N, int K, int nbx) {
  __shared__ u16 As[3][128 * 32];
  __shared__ u16 Bs[3][128 * 32];
  const int tid = threadIdx.x;
  const int lane = tid & 63, wid = tid >> 6;
  const int wr = wid >> 1, wc = wid & 1;
  const int l15 = lane & 15, lg = lane >> 4;
  const int lgx = lg ^ ((l15 >> 1) & 3);

  const int nwg = gridDim.x;
  const int cpx = nwg >> 3;
  const int p = blockIdx.x;
  const int wg = (p & 7) * cpx + (p >> 3);
  const int mblk = (wg / nbx) * 128, nblk = (wg % nbx) * 128;

  f32x4 acc[4][4] = {};

  const int srow = lane >> 2;
  const int skc = ((lane & 3) ^ ((srow >> 1) & 3)) * 8;
  const int rr0 = 32 * wid, rr1 = 32 * wid + 16;

  const u16* ap0 = A + (size_t)(mblk + rr0 + srow) * K + skc;
  const u16* ap1 = A + (size_t)(mblk + rr1 + srow) * K + skc;
  const u16* bp0 = Bt + (size_t)(nblk + rr0 + srow) * K + skc;
  const u16* bp1 = Bt + (size_t)(nblk + rr1 + srow) * K + skc;

#define GSTAGE(buf)                             \
  {                                             \
    gl2lds16(ap0, &As[buf][rr0 * 32]);          \
    gl2lds16(ap1, &As[buf][rr1 * 32]);          \
    gl2lds16(bp0, &Bs[buf][rr0 * 32]);          \
    gl2lds16(bp1, &Bs[buf][rr1 * 32]);          \
    ap0 += 32; ap1 += 32; bp0 += 32; bp1 += 32; \
  }

  const int nt = K >> 5;
  GSTAGE(0);
  GSTAGE(1);
  asm volatile("s_waitcnt vmcnt(4)" ::: "memory");
  __builtin_amdgcn_s_barrier();
  __builtin_amdgcn_sched_barrier(0);

  int cur = 0, stg = 2;
#pragma unroll 1
  for (int t = 0; t < nt; ++t) {
    const bool more = (t + 2 < nt);
    if (more) GSTAGE(stg);
    bf16x8 af[4], bfr[4];
#pragma unroll
    for (int i = 0; i < 4; ++i) {
      af[i] = as_bf(*(const uint4*)&As[cur][(64 * wr + 16 * i + l15) * 32 + 8 * lgx]);
      bfr[i] = as_bf(*(const uint4*)&Bs[cur][(64 * wc + 16 * i + l15) * 32 + 8 * lgx]);
    }
    __builtin_amdgcn_s_setprio(1);
#pragma unroll
    for (int mi = 0; mi < 4; ++mi)
#pragma unroll
      for (int ni = 0; ni < 4; ++ni)
        acc[mi][ni] = __builtin_amdgcn_mfma_f32_16x16x32_bf16(af[mi], bfr[ni], acc[mi][ni], 0, 0, 0);
    __builtin_amdgcn_s_setprio(0);
    if (more)
      asm volatile("s_waitcnt vmcnt(4)" ::: "memory");
    else
      asm volatile("s_waitcnt vmcnt(0)" ::: "memory");
    __builtin_amdgcn_s_barrier();
    __builtin_amdgcn_sched_barrier(0);
    cur = (cur == 2) ? 0 : cur + 1;
    stg = (stg == 2) ? 0 : stg + 1;
  }
#undef GSTAGE

#pragma unroll
  for (int ni = 0; ni < 4; ++ni) {
    const int col = nblk + 64 * wc + 16 * ni + l15;
    float bias;
    if (MODE == 0) {
      if (col < 768) bias = b0[col] * (0.125f * L2E);
      else if (col < 1536) bias = b1[col - 768];
      else bias = b2[col - 1536];
    } else {
      bias = b0[col];
    }
#pragma unroll
    for (int mi = 0; mi < 4; ++mi) {
#pragma unroll
      for (int r = 0; r < 4; ++r) {
        const int row = mblk + 64 * wr + 16 * mi + 4 * lg + r;
        const float v = acc[mi][ni][r] + bias;
        if (MODE == 0)
          ((u16*)Cout)[(size_t)row * N + col] = f2bf(v);
        else
          ((float*)Cout)[(size_t)row * N + col] = v;
      }
    }
  }
}

// ---------------- V transpose: vt[b][h][hd][s] = qkv[b][s][1536 + h*64 + hd] ----------------
__global__ void tr_v(const u16* __restrict__ qkv, u16* __restrict__ vt) {
  __shared__ u16 t[64][72];
  const int tid = threadIdx.x;
  const int st = blockIdx.x, h = blockIdx.y, b = blockIdx.z;
  const u16* vsrc = qkv + (size_t)b * 2048 * 2304 + 1536 + h * 64;
  const int s0 = st * 64;
#pragma unroll
  for (int i = 0; i < 2; ++i) {
    const int seg = tid + 256 * i;
    const int row = seg >> 3, slot = seg & 7;
    *(uint4*)&t[row][slot * 8] = *(const uint4*)(vsrc + (size_t)(s0 + row) * 2304 + slot * 8);
  }
  __syncthreads();
  u16* dst = vt + (size_t)(b * 12 + h) * 64 * 2048;
#pragma unroll
  for (int i = 0; i < 2; ++i) {
    const int seg = tid + 256 * i;
    const int hd = seg >> 3, j0 = (seg & 7) * 8;
    u16x8 o;
#pragma unroll
    for (int j = 0; j < 8; ++j) o[j] = t[j0 + j][hd];
    *(u16x8*)(dst + (size_t)hd * 2048 + s0 + j0) = o;
  }
}

// ---------------- flash attention v6 (R11): static-max softmax, p = 2^s ----------------
__global__ void __launch_bounds__(256, 3)
attn_fwd(const u16* __restrict__ qkv, const u16* __restrict__ vt, u16* __restrict__ ctx) {
  __shared__ u16 Ks[2][64 * 64];
  __shared__ u16 Vs[2][64 * 64];

  const int tid = threadIdx.x;
  const int lane = tid & 63, wid = tid >> 6;
  const int l31 = lane & 31, H = lane >> 5;
  const int r7 = l31 & 7;

  const int p = blockIdx.x;
  const int l = 96 * (p & 7) + (p >> 3);
  const int qb = l & 15;
  const int hb = l >> 4;
  const int h = hb % 12;
  const int b = hb / 12;

  const u16* qbase = qkv + (size_t)b * 2048 * 2304 + h * 64;
  const u16* kbase = qbase + 768;
  const u16* vbase = vt + (size_t)(b * 12 + h) * 64 * 2048;

  const int srow = tid >> 3;
  const int sx = (tid & 7) ^ (srow & 7);
  const int dseg = (tid & ~63) * 8;

  const u16* kp0 = kbase + (size_t)srow * 2304 + 8 * sx;
  const u16* kp1 = kbase + (size_t)(srow + 32) * 2304 + 8 * sx;
  const u16* vp0 = vbase + (size_t)srow * 2048 + 8 * sx;
  const u16* vp1 = vbase + (size_t)(srow + 32) * 2048 + 8 * sx;

  unsigned koff[2][4];
#pragma unroll
  for (int t32 = 0; t32 < 2; ++t32)
#pragma unroll
    for (int ks = 0; ks < 4; ++ks)
      koff[t32][ks] = (32 * t32 + l31) * 64 + 8 * ((2 * ks + H) ^ r7);

  const int q0 = qb * 128 + wid * 32;
  bf16x8 qf[4];
#pragma unroll
  for (int ks = 0; ks < 4; ++ks)
    qf[ks] = as_bf(*(const uint4*)(qbase + (size_t)(q0 + l31) * 2304 + 16 * ks + 8 * H));

  float lsum = 0.f;
  f32x16 o[2] = {};

#define STAGE(buf)                              \
  {                                             \
    gl2lds16(kp0, &Ks[buf][dseg]);              \
    gl2lds16(kp1, &Ks[buf][dseg + 2048]);       \
    gl2lds16(vp0, &Vs[buf][dseg]);              \
    gl2lds16(vp1, &Vs[buf][dseg + 2048]);       \
    kp0 += 64 * 2304; kp1 += 64 * 2304;         \
    vp0 += 64; vp1 += 64;                       \
  }

#define PHASE(CUR)                                                                        \
  {                                                                                       \
    f32x16 st[2] = {};                                                                    \
    __builtin_amdgcn_s_setprio(1);                                                        \
    _Pragma("unroll") for (int k32 = 0; k32 < 2; ++k32)                                   \
        _Pragma("unroll") for (int ks = 0; ks < 4; ++ks) {                                \
      bf16x8 kf = as_bf(*(const uint4*)&Ks[CUR][koff[k32][ks]]);                          \
      st[k32] = __builtin_amdgcn_mfma_f32_32x32x16_bf16(kf, qf[ks], st[k32], 0, 0, 0);    \
    }                                                                                     \
    __builtin_amdgcn_s_setprio(0);                                                        \
    float s0 = 0.f, s1 = 0.f, s2 = 0.f, s3 = 0.f;                                         \
    _Pragma("unroll") for (int k32 = 0; k32 < 2; ++k32)                                   \
        _Pragma("unroll") for (int r = 0; r < 16; r += 4) {                               \
      float e0 = EXP2(st[k32][r + 0]);                                                    \
      float e1 = EXP2(st[k32][r + 1]);                                                    \
      float e2 = EXP2(st[k32][r + 2]);                                                    \
      float e3 = EXP2(st[k32][r + 3]);                                                    \
      st[k32][r + 0] = e0; st[k32][r + 1] = e1;                                           \
      st[k32][r + 2] = e2; st[k32][r + 3] = e3;                                           \
      s0 += e0; s1 += e1; s2 += e2; s3 += e3;                                             \
    }                                                                                     \
    lsum += (s0 + s1) + (s2 + s3);                                                        \
    bf16x8 pf[4];                                                                         \
    _Pragma("unroll") for (int ks = 0; ks < 4; ++ks) {                                    \
      const int k32 = ks >> 1, rb = 8 * (ks & 1);                                         \
      unsigned a0 = pk2(st[k32][rb + 0], st[k32][rb + 1]);                                \
      unsigned a1 = pk2(st[k32][rb + 2], st[k32][rb + 3]);                                \
      unsigned a2 = pk2(st[k32][rb + 4], st[k32][rb + 5]);                                \
      unsigned a3 = pk2(st[k32][rb + 6], st[k32][rb + 7]);                                \
      u32x2 s02 = plswap(a0, a2);                                                         \
      u32x2 s13 = plswap(a1, a3);                                                         \
      uint4 w;                                                                            \
      w.x = s02.x; w.y = s13.x; w.z = s02.y; w.w = s13.y;                                 \
      pf[ks] = as_bf(w);                                                                  \
    }                                                                                     \
    __builtin_amdgcn_s_setprio(1);                                                        \
    _Pragma("unroll") for (int d32 = 0; d32 < 2; ++d32)                                   \
        _Pragma("unroll") for (int ks = 0; ks < 4; ++ks) {                                \
      bf16x8 vf = as_bf(*(const uint4*)&Vs[CUR][koff[d32][ks]]);                          \
      o[d32] = __builtin_amdgcn_mfma_f32_32x32x16_bf16(vf, pf[ks], o[d32], 0, 0, 0);      \
    }                                                                                     \
    __builtin_amdgcn_s_setprio(0);                                                        \
    __syncthreads();                                                                      \
  }

  STAGE(0);
  __syncthreads();

#pragma unroll 1
  for (int cc = 0; cc < 16; ++cc) {
    const int c2 = 2 * cc;
    STAGE(1);
    PHASE(0);
    if (c2 + 2 < 32) STAGE(0);
    PHASE(1);
  }
#undef PHASE
#undef STAGE

  const float ls = lsum + __shfl_xor(lsum, 32, 64);
  const float inv = 1.0f / ls;
  const size_t rowoff = ((size_t)b * 2048 + q0 + l31) * 768 + h * 64;
#pragma unroll
  for (int d32 = 0; d32 < 2; ++d32)
#pragma unroll
    for (int g = 0; g < 4; ++g) {
      uint2 w;
      w.x = pk2(o[d32][4 * g + 0] * inv, o[d32][4 * g + 1] * inv);
      w.y = pk2(o[d32][4 * g + 2] * inv, o[d32][4 * g + 3] * inv);
      *(uint2*)&ctx[rowoff + 32 * d32 + 8 * g + 4 * H] = w;
    }
}

// ---------------- launch ----------------
extern "C" void kernel_launch(void* const* d_in, const int* in_sizes, int n_in,
                              void* d_out, int out_size, void* d_ws, size_t ws_size,
                              hipStream_t stream) {
  const float* hs = (const float*)d_in[0];
  const float* Wq = (const float*)d_in[1];
  const float* bq = (const float*)d_in[2];
  const float* Wk = (const float*)d_in[3];
  const float* bk = (const float*)d_in[4];
  const float* Wv = (const float*)d_in[5];
  const float* bv = (const float*)d_in[6];
  const float* Wo = (const float*)d_in[7];
  const float* bo = (const float*)d_in[8];

  char* ws = (char*)d_ws;
  u16* hsb = (u16*)ws;                       // 8192*768 bf16
  u16* wt  = (u16*)(ws + 12582912);          // 2304*768 bf16
  u16* wot = (u16*)(ws + 16121856);          // 768*768 bf16
  u16* qkv = (u16*)(ws + 17301504);          // 8192*2304 bf16
  u16* vt  = (u16*)(ws + 55050240);          // 48*64*2048 bf16
  u16* ctx = (u16*)(ws + 67633152);          // 8192*768 bf16

  prep<<<dim3(8448), dim3(256), 0, stream>>>(hs, Wq, Wk, Wv, Wo, hsb, wt, wot);
  gemm256<0><<<dim3(288), dim3(512), 131072, stream>>>(hsb, wt, bq, bk, bv, (void*)qkv,
                                                       8192, 2304, 768, 9);
  tr_v<<<dim3(32, 12, 4), dim3(256), 0, stream>>>(qkv, vt);
  attn_fwd<<<dim3(768), dim3(256), 0, stream>>>(qkv, vt, ctx);
  gemm_bt<1><<<dim3(6 * 64), dim3(256), 0, stream>>>(ctx, wot, bo, bo, bo, d_out,
                                                     8192, 768, 768, 6);
}

// Round 15
// 150.313 us; speedup vs baseline: 1.4564x; 1.1952x over previous
//
#include <hip/hip_runtime.h>

typedef unsigned short u16;
typedef __attribute__((ext_vector_type(4))) float f32x4;
typedef __attribute__((ext_vector_type(16))) float f32x16;
typedef __attribute__((ext_vector_type(8))) __bf16 bf16x8;
typedef __attribute__((ext_vector_type(8))) unsigned short u16x8;
typedef __attribute__((ext_vector_type(2))) unsigned u32x2;

#define L2E 1.44269504088896340736f

#if __has_builtin(__builtin_amdgcn_exp2f)
#define EXP2(x) __builtin_amdgcn_exp2f(x)
#else
#define EXP2(x) exp2f(x)
#endif

__device__ __forceinline__ u16 f2bf(float f) {
  unsigned u = __float_as_uint(f);
  u += 0x7fffu + ((u >> 16) & 1u);
  return (u16)(u >> 16);
}

__device__ __forceinline__ unsigned pk2(float a, float b) {
  __bf16 x = (__bf16)a, y = (__bf16)b;
  unsigned short ux = __builtin_bit_cast(unsigned short, x);
  unsigned short uy = __builtin_bit_cast(unsigned short, y);
  return (unsigned)ux | ((unsigned)uy << 16);
}

__device__ __forceinline__ bf16x8 as_bf(uint4 v) { return __builtin_bit_cast(bf16x8, v); }

__device__ __forceinline__ u32x2 plswap(unsigned a, unsigned b) {
#if __has_builtin(__builtin_amdgcn_permlane32_swap)
  auto t = __builtin_amdgcn_permlane32_swap(a, b, false, false);
  return __builtin_bit_cast(u32x2, t);
#else
  unsigned pa = (unsigned)__shfl_xor((int)a, 32, 64);
  unsigned pb = (unsigned)__shfl_xor((int)b, 32, 64);
  const bool hi = (threadIdx.x & 32) != 0;
  u32x2 r;
  r.x = hi ? pb : a;
  r.y = hi ? b : pa;
  return r;
#endif
}

__device__ __forceinline__ void gl2lds16(const void* g, void* l) {
  __builtin_amdgcn_global_load_lds((const __attribute__((address_space(1))) void*)g,
                                   (__attribute__((address_space(3))) void*)l, 16, 0, 0);
}

// ---------------- prep: cvt_hs (blocks 0..6143) + cvt_w (blocks 6144..8447) ----------------
__global__ void prep(const float* __restrict__ hs, const float* __restrict__ Wq,
                     const float* __restrict__ Wk, const float* __restrict__ Wv,
                     const float* __restrict__ Wo, u16* __restrict__ hsb,
                     u16* __restrict__ wt, u16* __restrict__ wot) {
  const int blk = blockIdx.x;
  const int tid = threadIdx.x;
  if (blk < 6144) {
    const int i = blk * 256 + tid;
    float4 v = ((const float4*)hs)[i];
    ushort4 o;
    o.x = f2bf(v.x); o.y = f2bf(v.y); o.z = f2bf(v.z); o.w = f2bf(v.w);
    ((ushort4*)hsb)[i] = o;
    return;
  }
  __shared__ float ts[32][33];
  const int idx = blk - 6144;
  const int w = idx / 576;
  const int rem = idx % 576;
  const int n0 = (rem % 24) * 32, k0 = (rem / 24) * 32;
  const float* src = (w == 0) ? Wq : (w == 1) ? Wk : (w == 2) ? Wv : Wo;
  u16* dst = (w < 3) ? (wt + (size_t)w * 768 * 768) : wot;
  const float scale = (w == 0) ? 0.125f * L2E : 1.0f;
  const int tx = tid & 31, ty = tid >> 5;
#pragma unroll
  for (int j = 0; j < 4; ++j)
    ts[ty + 8 * j][tx] = src[(size_t)(k0 + ty + 8 * j) * 768 + n0 + tx];
  __syncthreads();
#pragma unroll
  for (int j = 0; j < 4; ++j)
    dst[(size_t)(n0 + ty + 8 * j) * 768 + k0 + tx] = f2bf(ts[tx][ty + 8 * j] * scale);
}

// ---------------- GEMM v8: 128x128 triple-buffer + SWAPPED MFMA + full-line epilogue -------
// K-loop identical to the proven R11 kernel (counted vmcnt, slot-XOR swizzle, 0 conflicts).
// MFMA operands swapped: acc[mi][ni] = mfma(bfr[ni], af[mi], .) so lane reg r holds
// C[m = 16mi+l15][n = 16ni+4lg+r] -> 4 CONTIGUOUS cols per lane.
// MODE 0 (bf16 out): pack uint2 -> LDS tile (reuse staging LDS, pad 136) -> uint4
//   readback -> 256B full-row stores (kills the ~2x partial-line write amplification
//   measured on gemm256: WRITE 80MB vs 37.7MB actual).
// MODE 1 (f32 out): direct float4 stores (64B/row per instr, full lines).
template <int MODE>
__global__ void gemm_bt(const u16* __restrict__ A, const u16* __restrict__ Bt,
                        const float* __restrict__ b0, const float* __restrict__ b1,
                        const float* __restrict__ b2, void* __restrict__ Cout,
                        int M, int N, int K, int nbx) {
  __shared__ u16 sh[24576];  // 49152 B: As[3][4096] | Bs[3][4096]; reused as C-tile LDS
  const int tid = threadIdx.x;
  const int lane = tid & 63, wid = tid >> 6;
  const int wr = wid >> 1, wc = wid & 1;
  const int l15 = lane & 15, lg = lane >> 4;
  const int lgx = lg ^ ((l15 >> 1) & 3);

  const int nwg = gridDim.x;
  const int cpx = nwg >> 3;
  const int p = blockIdx.x;
  const int wg = (p & 7) * cpx + (p >> 3);
  const int mblk = (wg / nbx) * 128, nblk = (wg % nbx) * 128;

  f32x4 acc[4][4] = {};

  const int srow = lane >> 2;
  const int skc = ((lane & 3) ^ ((srow >> 1) & 3)) * 8;
  const int rr0 = 32 * wid, rr1 = 32 * wid + 16;

  const u16* ap0 = A + (size_t)(mblk + rr0 + srow) * K + skc;
  const u16* ap1 = A + (size_t)(mblk + rr1 + srow) * K + skc;
  const u16* bp0 = Bt + (size_t)(nblk + rr0 + srow) * K + skc;
  const u16* bp1 = Bt + (size_t)(nblk + rr1 + srow) * K + skc;

#define GSTAGE(buf)                                   \
  {                                                   \
    gl2lds16(ap0, &sh[(buf) * 4096 + rr0 * 32]);      \
    gl2lds16(ap1, &sh[(buf) * 4096 + rr1 * 32]);      \
    gl2lds16(bp0, &sh[12288 + (buf) * 4096 + rr0 * 32]); \
    gl2lds16(bp1, &sh[12288 + (buf) * 4096 + rr1 * 32]); \
    ap0 += 32; ap1 += 32; bp0 += 32; bp1 += 32;       \
  }

  const int nt = K >> 5;
  GSTAGE(0);
  GSTAGE(1);
  asm volatile("s_waitcnt vmcnt(4)" ::: "memory");
  __builtin_amdgcn_s_barrier();
  __builtin_amdgcn_sched_barrier(0);

  int cur = 0, stg = 2;
#pragma unroll 1
  for (int t = 0; t < nt; ++t) {
    const bool more = (t + 2 < nt);
    if (more) GSTAGE(stg);
    bf16x8 af[4], bfr[4];
#pragma unroll
    for (int i = 0; i < 4; ++i) {
      af[i] = as_bf(*(const uint4*)&sh[cur * 4096 + (64 * wr + 16 * i + l15) * 32 + 8 * lgx]);
      bfr[i] = as_bf(*(const uint4*)&sh[12288 + cur * 4096 + (64 * wc + 16 * i + l15) * 32 + 8 * lgx]);
    }
    __builtin_amdgcn_s_setprio(1);
#pragma unroll
    for (int mi = 0; mi < 4; ++mi)
#pragma unroll
      for (int ni = 0; ni < 4; ++ni)
        acc[mi][ni] = __builtin_amdgcn_mfma_f32_16x16x32_bf16(bfr[ni], af[mi], acc[mi][ni], 0, 0, 0);
    __builtin_amdgcn_s_setprio(0);
    if (more)
      asm volatile("s_waitcnt vmcnt(4)" ::: "memory");
    else
      asm volatile("s_waitcnt vmcnt(0)" ::: "memory");
    __builtin_amdgcn_s_barrier();
    __builtin_amdgcn_sched_barrier(0);
    cur = (cur == 2) ? 0 : cur + 1;
    stg = (stg == 2) ? 0 : stg + 1;
  }
#undef GSTAGE

  // bias source for this tile's 128-col span (region boundaries align to 128)
  const float* bsrc;
  float bscale = 1.0f;
  int boff = 0;
  if (MODE == 0) {
    if (nblk < 768) { bsrc = b0; bscale = 0.125f * L2E; boff = 0; }
    else if (nblk < 1536) { bsrc = b1; boff = 768; }
    else { bsrc = b2; boff = 1536; }
  } else {
    bsrc = b0; boff = 0;
  }

  if (MODE == 0) {
    // pack to LDS tile [128][136] (pad -> 2-way banks), then full-row uint4 stores
#pragma unroll
    for (int mi = 0; mi < 4; ++mi) {
#pragma unroll
      for (int ni = 0; ni < 4; ++ni) {
        const int ncol = nblk + 64 * wc + 16 * ni + 4 * lg;
        const float4 bb = *(const float4*)&bsrc[ncol - boff];
        uint2 w;
        w.x = pk2(acc[mi][ni][0] + bb.x * bscale, acc[mi][ni][1] + bb.y * bscale);
        w.y = pk2(acc[mi][ni][2] + bb.z * bscale, acc[mi][ni][3] + bb.w * bscale);
        *(uint2*)&sh[(64 * wr + 16 * mi + l15) * 136 + 64 * wc + 16 * ni + 4 * lg] = w;
      }
    }
    __syncthreads();
    u16* C = (u16*)Cout;
#pragma unroll
    for (int pp = 0; pp < 8; ++pp) {
      const int idx = pp * 256 + tid;
      const int row = idx >> 4, slot = idx & 15;
      uint4 v = *(const uint4*)&sh[row * 136 + slot * 8];
      *(uint4*)&C[(size_t)(mblk + row) * N + nblk + slot * 8] = v;
    }
  } else {
    // direct float4 stores: 4 contiguous cols per lane, 64B/row per instruction
    float* C = (float*)Cout;
#pragma unroll
    for (int mi = 0; mi < 4; ++mi) {
#pragma unroll
      for (int ni = 0; ni < 4; ++ni) {
        const int ncol = nblk + 64 * wc + 16 * ni + 4 * lg;
        const float4 bb = *(const float4*)&bsrc[ncol - boff];
        float4 v;
        v.x = acc[mi][ni][0] + bb.x;
        v.y = acc[mi][ni][1] + bb.y;
        v.z = acc[mi][ni][2] + bb.z;
        v.w = acc[mi][ni][3] + bb.w;
        *(float4*)&C[(size_t)(mblk + 64 * wr + 16 * mi + l15) * N + ncol] = v;
      }
    }
  }
}

// ---------------- V transpose: vt[b][h][hd][s] = qkv[b][s][1536 + h*64 + hd] ----------------
__global__ void tr_v(const u16* __restrict__ qkv, u16* __restrict__ vt) {
  __shared__ u16 t[64][72];
  const int tid = threadIdx.x;
  const int st = blockIdx.x, h = blockIdx.y, b = blockIdx.z;
  const u16* vsrc = qkv + (size_t)b * 2048 * 2304 + 1536 + h * 64;
  const int s0 = st * 64;
#pragma unroll
  for (int i = 0; i < 2; ++i) {
    const int seg = tid + 256 * i;
    const int row = seg >> 3, slot = seg & 7;
    *(uint4*)&t[row][slot * 8] = *(const uint4*)(vsrc + (size_t)(s0 + row) * 2304 + slot * 8);
  }
  __syncthreads();
  u16* dst = vt + (size_t)(b * 12 + h) * 64 * 2048;
#pragma unroll
  for (int i = 0; i < 2; ++i) {
    const int seg = tid + 256 * i;
    const int hd = seg >> 3, j0 = (seg & 7) * 8;
    u16x8 o;
#pragma unroll
    for (int j = 0; j < 8; ++j) o[j] = t[j0 + j][hd];
    *(u16x8*)(dst + (size_t)hd * 2048 + s0 + j0) = o;
  }
}

// ---------------- flash attention v6 (R11, frozen): static-max softmax, p = 2^s ------------
__global__ void __launch_bounds__(256, 3)
attn_fwd(const u16* __restrict__ qkv, const u16* __restrict__ vt, u16* __restrict__ ctx) {
  __shared__ u16 Ks[2][64 * 64];
  __shared__ u16 Vs[2][64 * 64];

  const int tid = threadIdx.x;
  const int lane = tid & 63, wid = tid >> 6;
  const int l31 = lane & 31, H = lane >> 5;
  const int r7 = l31 & 7;

  const int p = blockIdx.x;
  const int l = 96 * (p & 7) + (p >> 3);
  const int qb = l & 15;
  const int hb = l >> 4;
  const int h = hb % 12;
  const int b = hb / 12;

  const u16* qbase = qkv + (size_t)b * 2048 * 2304 + h * 64;
  const u16* kbase = qbase + 768;
  const u16* vbase = vt + (size_t)(b * 12 + h) * 64 * 2048;

  const int srow = tid >> 3;
  const int sx = (tid & 7) ^ (srow & 7);
  const int dseg = (tid & ~63) * 8;

  const u16* kp0 = kbase + (size_t)srow * 2304 + 8 * sx;
  const u16* kp1 = kbase + (size_t)(srow + 32) * 2304 + 8 * sx;
  const u16* vp0 = vbase + (size_t)srow * 2048 + 8 * sx;
  const u16* vp1 = vbase + (size_t)(srow + 32) * 2048 + 8 * sx;

  unsigned koff[2][4];
#pragma unroll
  for (int t32 = 0; t32 < 2; ++t32)
#pragma unroll
    for (int ks = 0; ks < 4; ++ks)
      koff[t32][ks] = (32 * t32 + l31) * 64 + 8 * ((2 * ks + H) ^ r7);

  const int q0 = qb * 128 + wid * 32;
  bf16x8 qf[4];
#pragma unroll
  for (int ks = 0; ks < 4; ++ks)
    qf[ks] = as_bf(*(const uint4*)(qbase + (size_t)(q0 + l31) * 2304 + 16 * ks + 8 * H));

  float lsum = 0.f;
  f32x16 o[2] = {};

#define STAGE(buf)                              \
  {                                             \
    gl2lds16(kp0, &Ks[buf][dseg]);              \
    gl2lds16(kp1, &Ks[buf][dseg + 2048]);       \
    gl2lds16(vp0, &Vs[buf][dseg]);              \
    gl2lds16(vp1, &Vs[buf][dseg + 2048]);       \
    kp0 += 64 * 2304; kp1 += 64 * 2304;         \
    vp0 += 64; vp1 += 64;                       \
  }

#define PHASE(CUR)                                                                        \
  {                                                                                       \
    f32x16 st[2] = {};                                                                    \
    __builtin_amdgcn_s_setprio(1);                                                        \
    _Pragma("unroll") for (int k32 = 0; k32 < 2; ++k32)                                   \
        _Pragma("unroll") for (int ks = 0; ks < 4; ++ks) {                                \
      bf16x8 kf = as_bf(*(const uint4*)&Ks[CUR][koff[k32][ks]]);                          \
      st[k32] = __builtin_amdgcn_mfma_f32_32x32x16_bf16(kf, qf[ks], st[k32], 0, 0, 0);    \
    }                                                                                     \
    __builtin_amdgcn_s_setprio(0);                                                        \
    float s0 = 0.f, s1 = 0.f, s2 = 0.f, s3 = 0.f;                                         \
    _Pragma("unroll") for (int k32 = 0; k32 < 2; ++k32)                                   \
        _Pragma("unroll") for (int r = 0; r < 16; r += 4) {                               \
      float e0 = EXP2(st[k32][r + 0]);                                                    \
      float e1 = EXP2(st[k32][r + 1]);                                                    \
      float e2 = EXP2(st[k32][r + 2]);                                                    \
      float e3 = EXP2(st[k32][r + 3]);                                                    \
      st[k32][r + 0] = e0; st[k32][r + 1] = e1;                                           \
      st[k32][r + 2] = e2; st[k32][r + 3] = e3;                                           \
      s0 += e0; s1 += e1; s2 += e2; s3 += e3;                                             \
    }                                                                                     \
    lsum += (s0 + s1) + (s2 + s3);                                                        \
    bf16x8 pf[4];                                                                         \
    _Pragma("unroll") for (int ks = 0; ks < 4; ++ks) {                                    \
      const int k32 = ks >> 1, rb = 8 * (ks & 1);                                         \
      unsigned a0 = pk2(st[k32][rb + 0], st[k32][rb + 1]);                                \
      unsigned a1 = pk2(st[k32][rb + 2], st[k32][rb + 3]);                                \
      unsigned a2 = pk2(st[k32][rb + 4], st[k32][rb + 5]);                                \
      unsigned a3 = pk2(st[k32][rb + 6], st[k32][rb + 7]);                                \
      u32x2 s02 = plswap(a0, a2);                                                         \
      u32x2 s13 = plswap(a1, a3);                                                         \
      uint4 w;                                                                            \
      w.x = s02.x; w.y = s13.x; w.z = s02.y; w.w = s13.y;                                 \
      pf[ks] = as_bf(w);                                                                  \
    }                                                                                     \
    __builtin_amdgcn_s_setprio(1);                                                        \
    _Pragma("unroll") for (int d32 = 0; d32 < 2; ++d32)                                   \
        _Pragma("unroll") for (int ks = 0; ks < 4; ++ks) {                                \
      bf16x8 vf = as_bf(*(const uint4*)&Vs[CUR][koff[d32][ks]]);                          \
      o[d32] = __builtin_amdgcn_mfma_f32_32x32x16_bf16(vf, pf[ks], o[d32], 0, 0, 0);      \
    }                                                                                     \
    __builtin_amdgcn_s_setprio(0);                                                        \
    __syncthreads();                                                                      \
  }

  STAGE(0);
  __syncthreads();

#pragma unroll 1
  for (int cc = 0; cc < 16; ++cc) {
    const int c2 = 2 * cc;
    STAGE(1);
    PHASE(0);
    if (c2 + 2 < 32) STAGE(0);
    PHASE(1);
  }
#undef PHASE
#undef STAGE

  const float ls = lsum + __shfl_xor(lsum, 32, 64);
  const float inv = 1.0f / ls;
  const size_t rowoff = ((size_t)b * 2048 + q0 + l31) * 768 + h * 64;
#pragma unroll
  for (int d32 = 0; d32 < 2; ++d32)
#pragma unroll
    for (int g = 0; g < 4; ++g) {
      uint2 w;
      w.x = pk2(o[d32][4 * g + 0] * inv, o[d32][4 * g + 1] * inv);
      w.y = pk2(o[d32][4 * g + 2] * inv, o[d32][4 * g + 3] * inv);
      *(uint2*)&ctx[rowoff + 32 * d32 + 8 * g + 4 * H] = w;
    }
}

// ---------------- launch ----------------
extern "C" void kernel_launch(void* const* d_in, const int* in_sizes, int n_in,
                              void* d_out, int out_size, void* d_ws, size_t ws_size,
                              hipStream_t stream) {
  const float* hs = (const float*)d_in[0];
  const float* Wq = (const float*)d_in[1];
  const float* bq = (const float*)d_in[2];
  const float* Wk = (const float*)d_in[3];
  const float* bk = (const float*)d_in[4];
  const float* Wv = (const float*)d_in[5];
  const float* bv = (const float*)d_in[6];
  const float* Wo = (const float*)d_in[7];
  const float* bo = (const float*)d_in[8];

  char* ws = (char*)d_ws;
  u16* hsb = (u16*)ws;                       // 8192*768 bf16
  u16* wt  = (u16*)(ws + 12582912);          // 2304*768 bf16
  u16* wot = (u16*)(ws + 16121856);          // 768*768 bf16
  u16* qkv = (u16*)(ws + 17301504);          // 8192*2304 bf16
  u16* vt  = (u16*)(ws + 55050240);          // 48*64*2048 bf16
  u16* ctx = (u16*)(ws + 67633152);          // 8192*768 bf16

  prep<<<dim3(8448), dim3(256), 0, stream>>>(hs, Wq, Wk, Wv, Wo, hsb, wt, wot);
  gemm_bt<0><<<dim3(18 * 64), dim3(256), 0, stream>>>(hsb, wt, bq, bk, bv, (void*)qkv,
                                                      8192, 2304, 768, 18);
  tr_v<<<dim3(32, 12, 4), dim3(256), 0, stream>>>(qkv, vt);
  attn_fwd<<<dim3(768), dim3(256), 0, stream>>>(qkv, vt, ctx);
  gemm_bt<1><<<dim3(6 * 64), dim3(256), 0, stream>>>(ctx, wot, bo, bo, bo, d_out,
                                                     8192, 768, 768, 6);
}